// Round 2
// baseline (2182.705 us; speedup 1.0000x reference)
//
#include <hip/hip_runtime.h>
#include <cstdint>
#include <cstddef>

// Problem constants
#define B_   2
#define S_   2048
#define D_   2048
#define H_   8
#define HD_  256
#define M_   (B_ * S_)        // 4096 rows
#define NQ_  (H_ * HD_)       // 2048
#define NKV_ 256

// ---------------------------------------------------------------------------
// SGEMM tile: C[row0:row0+128, col0:col0+128] = A(M x K) @ Bw(K x N)
// 256 threads, 8x8 micro-tiles, BK=16.
// ---------------------------------------------------------------------------
__device__ __forceinline__ void sgemm_tile(const float* __restrict__ A,
                                           const float* __restrict__ Bw,
                                           float* __restrict__ C,
                                           int N, int K, int row0, int col0)
{
    __shared__ float As[16][128];   // A transposed: As[k][m]
    __shared__ float Bs[16][128];   // Bs[k][n]

    const int tid = threadIdx.x;
    const int tx = tid & 15, ty = tid >> 4;

    const int a_r = tid >> 2;          // 0..63
    const int a_c = (tid & 3) << 2;    // 0,4,8,12
    const int b_r = tid >> 5;          // 0..7
    const int b_c = (tid & 31) << 2;   // 0..124

    const float* Ap = A + (size_t)row0 * K;
    const float* Bp = Bw + col0;

    float acc[8][8];
#pragma unroll
    for (int i = 0; i < 8; ++i)
#pragma unroll
        for (int j = 0; j < 8; ++j) acc[i][j] = 0.f;

    for (int k0 = 0; k0 < K; k0 += 16) {
        float4 av0 = *(const float4*)(Ap + (size_t)a_r * K + k0 + a_c);
        float4 av1 = *(const float4*)(Ap + (size_t)(a_r + 64) * K + k0 + a_c);
        float4 bv0 = *(const float4*)(Bp + (size_t)(k0 + b_r) * N + b_c);
        float4 bv1 = *(const float4*)(Bp + (size_t)(k0 + b_r + 8) * N + b_c);
        if (k0) __syncthreads();
        As[a_c + 0][a_r] = av0.x;
        As[a_c + 1][a_r] = av0.y;
        As[a_c + 2][a_r] = av0.z;
        As[a_c + 3][a_r] = av0.w;
        As[a_c + 0][a_r + 64] = av1.x;
        As[a_c + 1][a_r + 64] = av1.y;
        As[a_c + 2][a_r + 64] = av1.z;
        As[a_c + 3][a_r + 64] = av1.w;
        *(float4*)&Bs[b_r][b_c]     = bv0;
        *(float4*)&Bs[b_r + 8][b_c] = bv1;
        __syncthreads();
#pragma unroll
        for (int kk = 0; kk < 16; ++kk) {
            float a[8], b[8];
            *(float4*)(a)     = *(const float4*)&As[kk][ty * 8];
            *(float4*)(a + 4) = *(const float4*)&As[kk][ty * 8 + 4];
            *(float4*)(b)     = *(const float4*)&Bs[kk][tx * 8];
            *(float4*)(b + 4) = *(const float4*)&Bs[kk][tx * 8 + 4];
#pragma unroll
            for (int i = 0; i < 8; ++i)
#pragma unroll
                for (int j = 0; j < 8; ++j)
                    acc[i][j] += a[i] * b[j];
        }
    }

#pragma unroll
    for (int i = 0; i < 8; ++i) {
        float* crow = C + (size_t)(row0 + ty * 8 + i) * N + col0 + tx * 8;
        *(float4*)(crow)     = make_float4(acc[i][0], acc[i][1], acc[i][2], acc[i][3]);
        *(float4*)(crow + 4) = make_float4(acc[i][4], acc[i][5], acc[i][6], acc[i][7]);
    }
}

// Fused QKV projection: one grid covers Wq (16 col-blocks) + Wk (2) + Wv (2).
__global__ __launch_bounds__(256, 2) void qkv_gemm_kernel(
    const float* __restrict__ X,
    const float* __restrict__ Wq, const float* __restrict__ Wk,
    const float* __restrict__ Wv,
    float* __restrict__ Qo, float* __restrict__ Ko, float* __restrict__ Vo)
{
    const int bn = blockIdx.x;  // 0..19
    const float* Bw;
    float* C;
    int N, col0;
    if (bn < 16)      { Bw = Wq; C = Qo; N = NQ_;  col0 = bn * 128; }
    else if (bn < 18) { Bw = Wk; C = Ko; N = NKV_; col0 = (bn - 16) * 128; }
    else              { Bw = Wv; C = Vo; N = NKV_; col0 = (bn - 18) * 128; }
    sgemm_tile(X, Bw, C, N, D_, blockIdx.y * 128, col0);
}

__global__ __launch_bounds__(256, 2) void out_gemm_kernel(
    const float* __restrict__ Ctx, const float* __restrict__ Wo,
    float* __restrict__ Out)
{
    sgemm_tile(Ctx, Wo, Out, D_, NQ_, blockIdx.y * 128, blockIdx.x * 128);
}

// ---------------------------------------------------------------------------
// RoPE (in-place on Q and K). One block per (b,s) row, 128 threads = freq idx.
// ---------------------------------------------------------------------------
__global__ __launch_bounds__(128) void rope_kernel(float* __restrict__ Q,
                                                   float* __restrict__ Kc)
{
    const int row = blockIdx.x;          // b*S + s
    const int d = threadIdx.x;           // 0..127
    const int s = row & (S_ - 1);

    const float expo = (float)(2 * d) / (float)HD_;
    const float inv_freq = 1.0f / powf(10000.0f, expo);
    const float fr = (float)s * inv_freq;
    float sn, c;
    sincosf(fr, &sn, &c);

    float* qr = Q + (size_t)row * NQ_;
#pragma unroll
    for (int h = 0; h < H_; ++h) {
        float x0 = qr[h * HD_ + d];
        float x1 = qr[h * HD_ + d + 128];
        qr[h * HD_ + d]       = x0 * c - x1 * sn;
        qr[h * HD_ + d + 128] = x1 * c + x0 * sn;
    }
    float* kr = Kc + (size_t)row * HD_;
    float x0 = kr[d], x1 = kr[d + 128];
    kr[d]       = x0 * c - x1 * sn;
    kr[d + 128] = x1 * c + x0 * sn;
}

// ---------------------------------------------------------------------------
// Flash attention, fp32, causal, GQA(KV=1). 64x64 tiles, HD=256.
// Grid: 512 blocks (1D), 256 threads. Work-balance swizzle pairs qt / 31-qt.
// ---------------------------------------------------------------------------
#define QT_ 64
#define KT_ 64

__global__ __launch_bounds__(256) void attn_kernel(
    const float* __restrict__ Q, const float* __restrict__ K,
    const float* __restrict__ V, float* __restrict__ O)
{
    __shared__ float Qs[HD_][QT_];        // [d][q]     64 KiB
    __shared__ float KVs[KT_ * HD_];      // K: [d][k] ld=64 ; V: [k][c] ld=256
    __shared__ float Ps[QT_][KT_ + 4];    // padded     17 KiB

    const int tid = threadIdx.x;

    // balanced (qt, bh) decode: block i and i+256 get complementary qt
    const int u = blockIdx.x & 255;
    const int pair = blockIdx.x >> 8;         // 0 or 1
    const int qt_base = u & 31;
    const int qt = pair ? (31 - qt_base) : qt_base;
    const int bh = (u >> 5) + pair * 8;       // 0..15
    const int b = bh >> 3, h = bh & 7;

    const float* Qb = Q + ((size_t)(b * S_ + qt * QT_)) * NQ_ + h * HD_;
    const float* Kb = K + (size_t)b * S_ * HD_;
    const float* Vb = V + (size_t)b * S_ * HD_;
    float* Ob = O + ((size_t)(b * S_ + qt * QT_)) * NQ_ + h * HD_;

    // ---- stage Q tile, transposed ----
    {
        const int q = tid >> 2;
        const int fv = (tid & 3) << 2;
#pragma unroll
        for (int r = 0; r < 16; ++r) {
            const int dd = fv + r * 16;
            float4 v4 = *(const float4*)(Qb + (size_t)q * NQ_ + dd);
            Qs[dd + 0][q] = v4.x;
            Qs[dd + 1][q] = v4.y;
            Qs[dd + 2][q] = v4.z;
            Qs[dd + 3][q] = v4.w;
        }
    }

    const int tq = tid >> 4;       // 0..15
    const int tk = tid & 15;       // 0..15
    const int q0 = tq * 4, k0 = tk * 4;

    float m_i[4], l_i[4];
    float oacc[4][16];
#pragma unroll
    for (int i = 0; i < 4; ++i) {
        m_i[i] = -1e30f;
        l_i[i] = 0.f;
#pragma unroll
        for (int j = 0; j < 16; ++j) oacc[i][j] = 0.f;
    }

    const int nkt = qt + 1;
    for (int kt = 0; kt < nkt; ++kt) {
        __syncthreads();   // prev PV (or Q staging) complete
        // ---- stage K tile transposed: KVs[d*64 + k] ----
        {
            const int k = tid >> 2;
            const int fv = (tid & 3) << 2;
#pragma unroll
            for (int r = 0; r < 16; ++r) {
                const int dd = fv + r * 16;
                float4 v4 = *(const float4*)(Kb + (size_t)(kt * KT_ + k) * HD_ + dd);
                KVs[(dd + 0) * KT_ + k] = v4.x;
                KVs[(dd + 1) * KT_ + k] = v4.y;
                KVs[(dd + 2) * KT_ + k] = v4.z;
                KVs[(dd + 3) * KT_ + k] = v4.w;
            }
        }
        __syncthreads();

        // ---- scores: 4x4 micro-tile over d=256 ----
        float sc[4][4];
#pragma unroll
        for (int i = 0; i < 4; ++i)
#pragma unroll
            for (int j = 0; j < 4; ++j) sc[i][j] = 0.f;

#pragma unroll 8
        for (int dd = 0; dd < HD_; ++dd) {
            float qa[4], ka[4];
            *(float4*)qa = *(const float4*)&Qs[dd][q0];
            *(float4*)ka = *(const float4*)&KVs[dd * KT_ + k0];
#pragma unroll
            for (int i = 0; i < 4; ++i)
#pragma unroll
                for (int j = 0; j < 4; ++j)
                    sc[i][j] += qa[i] * ka[j];
        }

        const bool diag = (kt == qt);
#pragma unroll
        for (int i = 0; i < 4; ++i)
#pragma unroll
            for (int j = 0; j < 4; ++j) {
                float v = sc[i][j] * 0.0625f;   // 1/sqrt(256)
                if (diag && (k0 + j > q0 + i)) v = -1e30f;
                sc[i][j] = v;
            }

        // ---- online softmax (row groups of 16 lanes) ----
#pragma unroll
        for (int i = 0; i < 4; ++i) {
            float mx = fmaxf(fmaxf(sc[i][0], sc[i][1]), fmaxf(sc[i][2], sc[i][3]));
#pragma unroll
            for (int off = 1; off < 16; off <<= 1)
                mx = fmaxf(mx, __shfl_xor(mx, off, 64));
            const float mnew = fmaxf(m_i[i], mx);
            const float alpha = __expf(m_i[i] - mnew);
            float psum = 0.f;
#pragma unroll
            for (int j = 0; j < 4; ++j) {
                float p = __expf(sc[i][j] - mnew);
                sc[i][j] = p;
                psum += p;
            }
#pragma unroll
            for (int off = 1; off < 16; off <<= 1)
                psum += __shfl_xor(psum, off, 64);
            l_i[i] = l_i[i] * alpha + psum;
            m_i[i] = mnew;
#pragma unroll
            for (int j = 0; j < 16; ++j) oacc[i][j] *= alpha;
        }

        // ---- write P ----
#pragma unroll
        for (int i = 0; i < 4; ++i)
#pragma unroll
            for (int j = 0; j < 4; ++j)
                Ps[q0 + i][k0 + j] = sc[i][j];
        __syncthreads();

        // ---- stage V tile natural: KVs[k*256 + c] ----
        {
            const int k = tid >> 4;          // 0..15
            const int fv = tid & 15;         // 0..15
#pragma unroll
            for (int r = 0; r < 16; ++r) {
                const int kk = k + (r & 3) * 16;
                const int cc = (fv + (r >> 2) * 16) * 4;
                *(float4*)&KVs[kk * HD_ + cc] =
                    *(const float4*)(Vb + (size_t)(kt * KT_ + kk) * HD_ + cc);
            }
        }
        __syncthreads();

        // ---- PV: oacc[4 rows][cols tk*4 + jv*64 + jj] ----
#pragma unroll 4
        for (int k = 0; k < KT_; ++k) {
            float pr[4];
#pragma unroll
            for (int i = 0; i < 4; ++i) pr[i] = Ps[q0 + i][k];
#pragma unroll
            for (int jv = 0; jv < 4; ++jv) {
                float vv[4];
                *(float4*)vv = *(const float4*)&KVs[k * HD_ + tk * 4 + jv * 64];
#pragma unroll
                for (int i = 0; i < 4; ++i) {
                    oacc[i][jv * 4 + 0] += pr[i] * vv[0];
                    oacc[i][jv * 4 + 1] += pr[i] * vv[1];
                    oacc[i][jv * 4 + 2] += pr[i] * vv[2];
                    oacc[i][jv * 4 + 3] += pr[i] * vv[3];
                }
            }
        }
    }

    // ---- epilogue: divide by l, write context ----
#pragma unroll
    for (int i = 0; i < 4; ++i) {
        const float inv_l = 1.0f / l_i[i];
#pragma unroll
        for (int jv = 0; jv < 4; ++jv) {
            float4 o4;
            o4.x = oacc[i][jv * 4 + 0] * inv_l;
            o4.y = oacc[i][jv * 4 + 1] * inv_l;
            o4.z = oacc[i][jv * 4 + 2] * inv_l;
            o4.w = oacc[i][jv * 4 + 3] * inv_l;
            *(float4*)(Ob + (size_t)(q0 + i) * NQ_ + tk * 4 + jv * 64) = o4;
        }
    }
}

// ---------------------------------------------------------------------------
extern "C" void kernel_launch(void* const* d_in, const int* in_sizes, int n_in,
                              void* d_out, int out_size, void* d_ws, size_t ws_size,
                              hipStream_t stream)
{
    (void)in_sizes; (void)n_in; (void)out_size; (void)ws_size;

    const float* hidden = (const float*)d_in[0];
    // d_in[1] attention_mask: pure causal, synthesized in-kernel
    // d_in[2] position_ids:   arange(S), synthesized in-kernel
    const float* Wq = (const float*)d_in[3];
    const float* Wk = (const float*)d_in[4];
    const float* Wv = (const float*)d_in[5];
    const float* Wo = (const float*)d_in[6];
    float* out = (float*)d_out;

    float* Qw = (float*)d_ws;                       // 4096 x 2048
    float* Kw = Qw + (size_t)M_ * NQ_;              // 4096 x 256
    float* Vw = Kw + (size_t)M_ * NKV_;             // 4096 x 256
    float* Cw = Vw + (size_t)M_ * NKV_;             // 4096 x 2048

    qkv_gemm_kernel<<<dim3(20, M_ / 128), dim3(256), 0, stream>>>(
        hidden, Wq, Wk, Wv, Qw, Kw, Vw);

    rope_kernel<<<dim3(M_), dim3(128), 0, stream>>>(Qw, Kw);

    attn_kernel<<<dim3(512), dim3(256), 0, stream>>>(Qw, Kw, Vw, Cw);

    out_gemm_kernel<<<dim3(NQ_ / 128, M_ / 128), dim3(256), 0, stream>>>(
        Cw, Wo, out);
}

// Round 3
// 1347.783 us; speedup vs baseline: 1.6195x; 1.6195x over previous
//
#include <hip/hip_runtime.h>
#include <cstdint>
#include <cstddef>

// Problem constants
#define B_   2
#define S_   2048
#define D_   2048
#define H_   8
#define HD_  256
#define M_   (B_ * S_)        // 4096 rows
#define NQ_  (H_ * HD_)       // 2048
#define NKV_ 256

typedef unsigned short u16;
typedef __attribute__((ext_vector_type(8))) short short8v;   // 8 bf16 (4 VGPRs)
typedef __attribute__((ext_vector_type(4))) float f32x4;     // MFMA acc frag

__device__ __forceinline__ u16 f2bf_rn(float x) {
    unsigned int u = __float_as_uint(x);
    unsigned int r = u + 0x7FFFu + ((u >> 16) & 1u);
    return (u16)(r >> 16);
}
__device__ __forceinline__ float bf2f(u16 h) {
    return __uint_as_float(((unsigned int)h) << 16);
}

// ---------------------------------------------------------------------------
// split: fp32 [n] -> hi/lo bf16 [n].  8 elems per thread.
// ---------------------------------------------------------------------------
__global__ __launch_bounds__(256) void split_kernel(const float* __restrict__ in,
                                                    u16* __restrict__ hi,
                                                    u16* __restrict__ lo)
{
    const size_t i = ((size_t)blockIdx.x * 256 + threadIdx.x) * 8;
    float4 v0 = *(const float4*)(in + i);
    float4 v1 = *(const float4*)(in + i + 4);
    float xs[8] = {v0.x, v0.y, v0.z, v0.w, v1.x, v1.y, v1.z, v1.w};
    unsigned int hv[4], lv[4];
#pragma unroll
    for (int k = 0; k < 4; ++k) {
        u16 h0 = f2bf_rn(xs[2 * k]);
        u16 h1 = f2bf_rn(xs[2 * k + 1]);
        u16 l0 = f2bf_rn(xs[2 * k] - bf2f(h0));
        u16 l1 = f2bf_rn(xs[2 * k + 1] - bf2f(h1));
        hv[k] = (unsigned int)h0 | ((unsigned int)h1 << 16);
        lv[k] = (unsigned int)l0 | ((unsigned int)l1 << 16);
    }
    *(uint4*)(hi + i) = make_uint4(hv[0], hv[1], hv[2], hv[3]);
    *(uint4*)(lo + i) = make_uint4(lv[0], lv[1], lv[2], lv[3]);
}

// ---------------------------------------------------------------------------
// transpose+split: W [K][N] fp32 -> Th/Tl [N][K] bf16.  64x64 tiles via LDS.
// ---------------------------------------------------------------------------
__global__ __launch_bounds__(256) void tsplit_kernel(const float* __restrict__ W,
                                                     u16* __restrict__ Th,
                                                     u16* __restrict__ Tl,
                                                     int K, int N)
{
    __shared__ float t[64][65];
    const int kt = blockIdx.x, nt = blockIdx.y;
    const int c4 = (threadIdx.x & 15) * 4;   // col-in-tile (n on read, k on write)
    const int r  = threadIdx.x >> 4;         // 0..15

#pragma unroll
    for (int s = 0; s < 4; ++s) {
        const int kk = r + s * 16;
        float4 v = *(const float4*)(W + (size_t)(kt * 64 + kk) * N + nt * 64 + c4);
        t[kk][c4 + 0] = v.x;
        t[kk][c4 + 1] = v.y;
        t[kk][c4 + 2] = v.z;
        t[kk][c4 + 3] = v.w;
    }
    __syncthreads();
#pragma unroll
    for (int s = 0; s < 4; ++s) {
        const int nn = r + s * 16;           // n-local row of output
        unsigned int hv[2], lv[2];
#pragma unroll
        for (int p = 0; p < 2; ++p) {
            u16 h0, h1, l0, l1;
            float x0 = t[c4 + 2 * p][nn];
            float x1 = t[c4 + 2 * p + 1][nn];
            h0 = f2bf_rn(x0); l0 = f2bf_rn(x0 - bf2f(h0));
            h1 = f2bf_rn(x1); l1 = f2bf_rn(x1 - bf2f(h1));
            hv[p] = (unsigned int)h0 | ((unsigned int)h1 << 16);
            lv[p] = (unsigned int)l0 | ((unsigned int)l1 << 16);
        }
        u16* ph = Th + (size_t)(nt * 64 + nn) * K + kt * 64 + c4;
        u16* pl = Tl + (size_t)(nt * 64 + nn) * K + kt * 64 + c4;
        *(uint2*)ph = make_uint2(hv[0], hv[1]);
        *(uint2*)pl = make_uint2(lv[0], lv[1]);
    }
}

// ---------------------------------------------------------------------------
// Split-bf16 MFMA GEMM tile: C[128m x 128n] = A @ B^T with
// A = Ah+Al [M][Kd] bf16, B supplied transposed: Bh/Bl [N][Kd] bf16.
// C = Ah*Bh + Ah*Bl + Al*Bh  (error ~2^-18, fp32-equivalent).
// 256 threads = 4 waves (2x2), each wave 64x64 out = 4x4 frags of 16x16.
// ---------------------------------------------------------------------------
__device__ __forceinline__ void mfma_gemm_tile(
    const u16* __restrict__ Ah, const u16* __restrict__ Al,
    const u16* __restrict__ Bh, const u16* __restrict__ Bl,
    float* __restrict__ C, const int Kd, const int ldc,
    const int bm0, const int bn0)
{
    __shared__ u16 ldsAh[128 * 32];
    __shared__ u16 ldsAl[128 * 32];
    __shared__ u16 ldsBh[128 * 32];
    __shared__ u16 ldsBl[128 * 32];

    const int tid  = threadIdx.x;
    const int lane = tid & 63;
    const int w    = tid >> 6;
    const int wr   = w >> 1, wc = w & 1;

    // staging map: rows rs, rs+64; 8-bf16 chunk qs
    const int rs = tid >> 2;          // 0..63
    const int qs = (tid & 3) * 8;     // bf16 elems

    const u16* pAh = Ah + (size_t)(bm0 + rs) * Kd + qs;
    const u16* pAl = Al + (size_t)(bm0 + rs) * Kd + qs;
    const u16* pBh = Bh + (size_t)(bn0 + rs) * Kd + qs;
    const u16* pBl = Bl + (size_t)(bn0 + rs) * Kd + qs;
    const size_t rowskip = (size_t)64 * Kd;

    f32x4 acc[4][4];
#pragma unroll
    for (int i = 0; i < 4; ++i)
#pragma unroll
        for (int j = 0; j < 4; ++j) acc[i][j] = (f32x4){0.f, 0.f, 0.f, 0.f};

    // fragment read coords: lane holds row (lane&15), k = (lane>>4)*8 + j
    const int fr = lane & 15;
    const int kb = (lane >> 4) * 8;

    for (int k0 = 0; k0 < Kd; k0 += 32) {
        uint4 sAh0 = *(const uint4*)(pAh);
        uint4 sAh1 = *(const uint4*)(pAh + rowskip);
        uint4 sAl0 = *(const uint4*)(pAl);
        uint4 sAl1 = *(const uint4*)(pAl + rowskip);
        uint4 sBh0 = *(const uint4*)(pBh);
        uint4 sBh1 = *(const uint4*)(pBh + rowskip);
        uint4 sBl0 = *(const uint4*)(pBl);
        uint4 sBl1 = *(const uint4*)(pBl + rowskip);
        pAh += 32; pAl += 32; pBh += 32; pBl += 32;

        if (k0) __syncthreads();
        *(uint4*)&ldsAh[rs * 32 + qs]        = sAh0;
        *(uint4*)&ldsAh[(rs + 64) * 32 + qs] = sAh1;
        *(uint4*)&ldsAl[rs * 32 + qs]        = sAl0;
        *(uint4*)&ldsAl[(rs + 64) * 32 + qs] = sAl1;
        *(uint4*)&ldsBh[rs * 32 + qs]        = sBh0;
        *(uint4*)&ldsBh[(rs + 64) * 32 + qs] = sBh1;
        *(uint4*)&ldsBl[rs * 32 + qs]        = sBl0;
        *(uint4*)&ldsBl[(rs + 64) * 32 + qs] = sBl1;
        __syncthreads();

        short8v a_h[4], a_l[4], b_h[4], b_l[4];
#pragma unroll
        for (int f = 0; f < 4; ++f) {
            const int ra = (wr * 64 + f * 16 + fr) * 32 + kb;
            const int rb = (wc * 64 + f * 16 + fr) * 32 + kb;
            a_h[f] = *(const short8v*)&ldsAh[ra];
            a_l[f] = *(const short8v*)&ldsAl[ra];
            b_h[f] = *(const short8v*)&ldsBh[rb];
            b_l[f] = *(const short8v*)&ldsBl[rb];
        }
#pragma unroll
        for (int i = 0; i < 4; ++i)
#pragma unroll
            for (int j = 0; j < 4; ++j) {
                acc[i][j] = __builtin_amdgcn_mfma_f32_16x16x32_bf16(a_h[i], b_h[j], acc[i][j], 0, 0, 0);
                acc[i][j] = __builtin_amdgcn_mfma_f32_16x16x32_bf16(a_h[i], b_l[j], acc[i][j], 0, 0, 0);
                acc[i][j] = __builtin_amdgcn_mfma_f32_16x16x32_bf16(a_l[i], b_h[j], acc[i][j], 0, 0, 0);
            }
    }

    // epilogue: verified C/D map — col = lane&15, row = (lane>>4)*4 + reg
    const int cr = (lane >> 4) * 4;
    const int cc = lane & 15;
#pragma unroll
    for (int i = 0; i < 4; ++i)
#pragma unroll
        for (int j = 0; j < 4; ++j) {
#pragma unroll
            for (int r = 0; r < 4; ++r) {
                C[(size_t)(bm0 + wr * 64 + i * 16 + cr + r) * ldc
                  + (bn0 + wc * 64 + j * 16 + cc)] = acc[i][j][r];
            }
        }
}

// Fused QKV projection: Wq (16 col-tiles) + Wk (2) + Wv (2) in one grid.
__global__ __launch_bounds__(256, 2) void qkv_mfma_kernel(
    const u16* __restrict__ Xh, const u16* __restrict__ Xl,
    const u16* __restrict__ WqTh, const u16* __restrict__ WqTl,
    const u16* __restrict__ WkTh, const u16* __restrict__ WkTl,
    const u16* __restrict__ WvTh, const u16* __restrict__ WvTl,
    float* __restrict__ Qo, float* __restrict__ Ko, float* __restrict__ Vo)
{
    const int bn = blockIdx.x;  // 0..19
    const u16 *Bh, *Bl; float* C; int ldc, col0;
    if (bn < 16)      { Bh = WqTh; Bl = WqTl; C = Qo; ldc = NQ_;  col0 = bn * 128; }
    else if (bn < 18) { Bh = WkTh; Bl = WkTl; C = Ko; ldc = NKV_; col0 = (bn - 16) * 128; }
    else              { Bh = WvTh; Bl = WvTl; C = Vo; ldc = NKV_; col0 = (bn - 18) * 128; }
    mfma_gemm_tile(Xh, Xl, Bh, Bl, C, D_, ldc, blockIdx.y * 128, col0);
}

__global__ __launch_bounds__(256, 2) void out_mfma_kernel(
    const u16* __restrict__ Ch, const u16* __restrict__ Cl,
    const u16* __restrict__ WoTh, const u16* __restrict__ WoTl,
    float* __restrict__ Out)
{
    mfma_gemm_tile(Ch, Cl, WoTh, WoTl, Out, NQ_, D_, blockIdx.y * 128, blockIdx.x * 128);
}

// ---------------------------------------------------------------------------
// RoPE (in-place on Q and K). One block per (b,s) row, 128 threads = freq idx.
// ---------------------------------------------------------------------------
__global__ __launch_bounds__(128) void rope_kernel(float* __restrict__ Q,
                                                   float* __restrict__ Kc)
{
    const int row = blockIdx.x;          // b*S + s
    const int d = threadIdx.x;           // 0..127
    const int s = row & (S_ - 1);

    const float expo = (float)(2 * d) / (float)HD_;
    const float inv_freq = 1.0f / powf(10000.0f, expo);
    const float fr = (float)s * inv_freq;
    float sn, c;
    sincosf(fr, &sn, &c);

    float* qr = Q + (size_t)row * NQ_;
#pragma unroll
    for (int h = 0; h < H_; ++h) {
        float x0 = qr[h * HD_ + d];
        float x1 = qr[h * HD_ + d + 128];
        qr[h * HD_ + d]       = x0 * c - x1 * sn;
        qr[h * HD_ + d + 128] = x1 * c + x0 * sn;
    }
    float* kr = Kc + (size_t)row * HD_;
    float x0 = kr[d], x1 = kr[d + 128];
    kr[d]       = x0 * c - x1 * sn;
    kr[d + 128] = x1 * c + x0 * sn;
}

// ---------------------------------------------------------------------------
// Flash attention, fp32, causal, GQA(KV=1). 64x64 tiles, HD=256. (unchanged)
// ---------------------------------------------------------------------------
#define QT_ 64
#define KT_ 64

__global__ __launch_bounds__(256) void attn_kernel(
    const float* __restrict__ Q, const float* __restrict__ K,
    const float* __restrict__ V, float* __restrict__ O)
{
    __shared__ float Qs[HD_][QT_];        // [d][q]     64 KiB
    __shared__ float KVs[KT_ * HD_];      // K: [d][k] ld=64 ; V: [k][c] ld=256
    __shared__ float Ps[QT_][KT_ + 4];    // padded     17 KiB

    const int tid = threadIdx.x;

    const int u = blockIdx.x & 255;
    const int pair = blockIdx.x >> 8;         // 0 or 1
    const int qt_base = u & 31;
    const int qt = pair ? (31 - qt_base) : qt_base;
    const int bh = (u >> 5) + pair * 8;       // 0..15
    const int b = bh >> 3, h = bh & 7;

    const float* Qb = Q + ((size_t)(b * S_ + qt * QT_)) * NQ_ + h * HD_;
    const float* Kb = K + (size_t)b * S_ * HD_;
    const float* Vb = V + (size_t)b * S_ * HD_;
    float* Ob = O + ((size_t)(b * S_ + qt * QT_)) * NQ_ + h * HD_;

    {
        const int q = tid >> 2;
        const int fv = (tid & 3) << 2;
#pragma unroll
        for (int r = 0; r < 16; ++r) {
            const int dd = fv + r * 16;
            float4 v4 = *(const float4*)(Qb + (size_t)q * NQ_ + dd);
            Qs[dd + 0][q] = v4.x;
            Qs[dd + 1][q] = v4.y;
            Qs[dd + 2][q] = v4.z;
            Qs[dd + 3][q] = v4.w;
        }
    }

    const int tq = tid >> 4;       // 0..15
    const int tk = tid & 15;       // 0..15
    const int q0 = tq * 4, k0 = tk * 4;

    float m_i[4], l_i[4];
    float oacc[4][16];
#pragma unroll
    for (int i = 0; i < 4; ++i) {
        m_i[i] = -1e30f;
        l_i[i] = 0.f;
#pragma unroll
        for (int j = 0; j < 16; ++j) oacc[i][j] = 0.f;
    }

    const int nkt = qt + 1;
    for (int kt = 0; kt < nkt; ++kt) {
        __syncthreads();
        {
            const int k = tid >> 2;
            const int fv = (tid & 3) << 2;
#pragma unroll
            for (int r = 0; r < 16; ++r) {
                const int dd = fv + r * 16;
                float4 v4 = *(const float4*)(Kb + (size_t)(kt * KT_ + k) * HD_ + dd);
                KVs[(dd + 0) * KT_ + k] = v4.x;
                KVs[(dd + 1) * KT_ + k] = v4.y;
                KVs[(dd + 2) * KT_ + k] = v4.z;
                KVs[(dd + 3) * KT_ + k] = v4.w;
            }
        }
        __syncthreads();

        float sc[4][4];
#pragma unroll
        for (int i = 0; i < 4; ++i)
#pragma unroll
            for (int j = 0; j < 4; ++j) sc[i][j] = 0.f;

#pragma unroll 8
        for (int dd = 0; dd < HD_; ++dd) {
            float qa[4], ka[4];
            *(float4*)qa = *(const float4*)&Qs[dd][q0];
            *(float4*)ka = *(const float4*)&KVs[dd * KT_ + k0];
#pragma unroll
            for (int i = 0; i < 4; ++i)
#pragma unroll
                for (int j = 0; j < 4; ++j)
                    sc[i][j] += qa[i] * ka[j];
        }

        const bool diag = (kt == qt);
#pragma unroll
        for (int i = 0; i < 4; ++i)
#pragma unroll
            for (int j = 0; j < 4; ++j) {
                float v = sc[i][j] * 0.0625f;   // 1/sqrt(256)
                if (diag && (k0 + j > q0 + i)) v = -1e30f;
                sc[i][j] = v;
            }

#pragma unroll
        for (int i = 0; i < 4; ++i) {
            float mx = fmaxf(fmaxf(sc[i][0], sc[i][1]), fmaxf(sc[i][2], sc[i][3]));
#pragma unroll
            for (int off = 1; off < 16; off <<= 1)
                mx = fmaxf(mx, __shfl_xor(mx, off, 64));
            const float mnew = fmaxf(m_i[i], mx);
            const float alpha = __expf(m_i[i] - mnew);
            float psum = 0.f;
#pragma unroll
            for (int j = 0; j < 4; ++j) {
                float p = __expf(sc[i][j] - mnew);
                sc[i][j] = p;
                psum += p;
            }
#pragma unroll
            for (int off = 1; off < 16; off <<= 1)
                psum += __shfl_xor(psum, off, 64);
            l_i[i] = l_i[i] * alpha + psum;
            m_i[i] = mnew;
#pragma unroll
            for (int j = 0; j < 16; ++j) oacc[i][j] *= alpha;
        }

#pragma unroll
        for (int i = 0; i < 4; ++i)
#pragma unroll
            for (int j = 0; j < 4; ++j)
                Ps[q0 + i][k0 + j] = sc[i][j];
        __syncthreads();

        {
            const int k = tid >> 4;          // 0..15
            const int fv = tid & 15;         // 0..15
#pragma unroll
            for (int r = 0; r < 16; ++r) {
                const int kk = k + (r & 3) * 16;
                const int cc = (fv + (r >> 2) * 16) * 4;
                *(float4*)&KVs[kk * HD_ + cc] =
                    *(const float4*)(Vb + (size_t)(kt * KT_ + kk) * HD_ + cc);
            }
        }
        __syncthreads();

#pragma unroll 4
        for (int k = 0; k < KT_; ++k) {
            float pr[4];
#pragma unroll
            for (int i = 0; i < 4; ++i) pr[i] = Ps[q0 + i][k];
#pragma unroll
            for (int jv = 0; jv < 4; ++jv) {
                float vv[4];
                *(float4*)vv = *(const float4*)&KVs[k * HD_ + tk * 4 + jv * 64];
#pragma unroll
                for (int i = 0; i < 4; ++i) {
                    oacc[i][jv * 4 + 0] += pr[i] * vv[0];
                    oacc[i][jv * 4 + 1] += pr[i] * vv[1];
                    oacc[i][jv * 4 + 2] += pr[i] * vv[2];
                    oacc[i][jv * 4 + 3] += pr[i] * vv[3];
                }
            }
        }
    }

#pragma unroll
    for (int i = 0; i < 4; ++i) {
        const float inv_l = 1.0f / l_i[i];
#pragma unroll
        for (int jv = 0; jv < 4; ++jv) {
            float4 o4;
            o4.x = oacc[i][jv * 4 + 0] * inv_l;
            o4.y = oacc[i][jv * 4 + 1] * inv_l;
            o4.z = oacc[i][jv * 4 + 2] * inv_l;
            o4.w = oacc[i][jv * 4 + 3] * inv_l;
            *(float4*)(Ob + (size_t)(q0 + i) * NQ_ + tk * 4 + jv * 64) = o4;
        }
    }
}

// ---------------------------------------------------------------------------
extern "C" void kernel_launch(void* const* d_in, const int* in_sizes, int n_in,
                              void* d_out, int out_size, void* d_ws, size_t ws_size,
                              hipStream_t stream)
{
    (void)in_sizes; (void)n_in; (void)out_size; (void)ws_size;

    const float* hidden = (const float*)d_in[0];
    const float* Wq = (const float*)d_in[3];
    const float* Wk = (const float*)d_in[4];
    const float* Wv = (const float*)d_in[5];
    const float* Wo = (const float*)d_in[6];
    float* out = (float*)d_out;

    char* ws = (char*)d_ws;
    // fp32 intermediates
    float* Qw = (float*)(ws +          0);   // 4096x2048  33,554,432 B
    float* Kw = (float*)(ws +  33554432u);   // 4096x256    4,194,304 B
    float* Vw = (float*)(ws +  37748736u);   // 4096x256    4,194,304 B
    float* Cw = (float*)(ws +  41943040u);   // 4096x2048  33,554,432 B
    // bf16 hi/lo of A-side (X, then reused for Ctx)
    u16* Ah = (u16*)(ws +  75497472u);       // 4096x2048  16,777,216 B
    u16* Al = (u16*)(ws +  92274688u);       // 4096x2048  16,777,216 B
    // bf16 hi/lo transposed weights
    u16* WqTh = (u16*)(ws + 109051904u);     // 2048x2048   8,388,608 B
    u16* WqTl = (u16*)(ws + 117440512u);     //             8,388,608 B
    u16* WkTh = (u16*)(ws + 125829120u);     //  256x2048   1,048,576 B
    u16* WkTl = (u16*)(ws + 126877696u);
    u16* WvTh = (u16*)(ws + 127926272u);
    u16* WvTl = (u16*)(ws + 128974848u);     // end ≈ 130,023,424 B
    // Wo^T aliases Wq^T region (prep runs after qkv gemm has consumed Wq^T)
    u16* WoTh = WqTh;
    u16* WoTl = WqTl;

    // 1) split X -> Ah/Al
    split_kernel<<<dim3((M_ * D_) / (256 * 8)), dim3(256), 0, stream>>>(hidden, Ah, Al);

    // 2) transpose+split Wq, Wk, Wv
    tsplit_kernel<<<dim3(D_ / 64, NQ_ / 64),  dim3(256), 0, stream>>>(Wq, WqTh, WqTl, D_, NQ_);
    tsplit_kernel<<<dim3(D_ / 64, NKV_ / 64), dim3(256), 0, stream>>>(Wk, WkTh, WkTl, D_, NKV_);
    tsplit_kernel<<<dim3(D_ / 64, NKV_ / 64), dim3(256), 0, stream>>>(Wv, WvTh, WvTl, D_, NKV_);

    // 3) fused QKV projection (split-bf16 MFMA)
    qkv_mfma_kernel<<<dim3(20, M_ / 128), dim3(256), 0, stream>>>(
        Ah, Al, WqTh, WqTl, WkTh, WkTl, WvTh, WvTl, Qw, Kw, Vw);

    // 4) RoPE
    rope_kernel<<<dim3(M_), dim3(128), 0, stream>>>(Qw, Kw);

    // 5) flash attention
    attn_kernel<<<dim3(512), dim3(256), 0, stream>>>(Qw, Kw, Vw, Cw);

    // 6) split Ctx -> Ah/Al (region reuse; qkv gemm done with X)
    split_kernel<<<dim3((M_ * NQ_) / (256 * 8)), dim3(256), 0, stream>>>(Cw, Ah, Al);

    // 7) transpose+split Wo (into Wq^T region)
    tsplit_kernel<<<dim3(NQ_ / 64, D_ / 64), dim3(256), 0, stream>>>(Wo, WoTh, WoTl, NQ_, D_);

    // 8) output projection (split-bf16 MFMA)
    out_mfma_kernel<<<dim3(D_ / 128, M_ / 128), dim3(256), 0, stream>>>(
        Ah, Al, WoTh, WoTl, out);
}

// Round 4
// 678.870 us; speedup vs baseline: 3.2152x; 1.9853x over previous
//
#include <hip/hip_runtime.h>
#include <cstdint>
#include <cstddef>

// Problem constants
#define B_   2
#define S_   2048
#define D_   2048
#define H_   8
#define HD_  256
#define M_   (B_ * S_)        // 4096 rows
#define NQ_  (H_ * HD_)       // 2048
#define NKV_ 256

typedef unsigned short u16;
typedef __attribute__((ext_vector_type(8))) short short8v;   // 8 bf16 (4 VGPRs)
typedef __attribute__((ext_vector_type(4))) float f32x4;     // MFMA acc frag

__device__ __forceinline__ u16 f2bf_rn(float x) {
    unsigned int u = __float_as_uint(x);
    unsigned int r = u + 0x7FFFu + ((u >> 16) & 1u);
    return (u16)(r >> 16);
}
__device__ __forceinline__ float bf2f(u16 h) {
    return __uint_as_float(((unsigned int)h) << 16);
}

// ---------------------------------------------------------------------------
// split: fp32 [n] -> hi/lo bf16 [n].  8 elems per thread.
// ---------------------------------------------------------------------------
__global__ __launch_bounds__(256) void split_kernel(const float* __restrict__ in,
                                                    u16* __restrict__ hi,
                                                    u16* __restrict__ lo)
{
    const size_t i = ((size_t)blockIdx.x * 256 + threadIdx.x) * 8;
    float4 v0 = *(const float4*)(in + i);
    float4 v1 = *(const float4*)(in + i + 4);
    float xs[8] = {v0.x, v0.y, v0.z, v0.w, v1.x, v1.y, v1.z, v1.w};
    unsigned int hv[4], lv[4];
#pragma unroll
    for (int k = 0; k < 4; ++k) {
        u16 h0 = f2bf_rn(xs[2 * k]);
        u16 h1 = f2bf_rn(xs[2 * k + 1]);
        u16 l0 = f2bf_rn(xs[2 * k] - bf2f(h0));
        u16 l1 = f2bf_rn(xs[2 * k + 1] - bf2f(h1));
        hv[k] = (unsigned int)h0 | ((unsigned int)h1 << 16);
        lv[k] = (unsigned int)l0 | ((unsigned int)l1 << 16);
    }
    *(uint4*)(hi + i) = make_uint4(hv[0], hv[1], hv[2], hv[3]);
    *(uint4*)(lo + i) = make_uint4(lv[0], lv[1], lv[2], lv[3]);
}

// ---------------------------------------------------------------------------
// transpose+split: W [K][N] fp32 -> Th/Tl [N][K] bf16.  64x64 tiles via LDS.
// ---------------------------------------------------------------------------
__global__ __launch_bounds__(256) void tsplit_kernel(const float* __restrict__ W,
                                                     u16* __restrict__ Th,
                                                     u16* __restrict__ Tl,
                                                     int K, int N)
{
    __shared__ float t[64][65];
    const int kt = blockIdx.x, nt = blockIdx.y;
    const int c4 = (threadIdx.x & 15) * 4;
    const int r  = threadIdx.x >> 4;

#pragma unroll
    for (int s = 0; s < 4; ++s) {
        const int kk = r + s * 16;
        float4 v = *(const float4*)(W + (size_t)(kt * 64 + kk) * N + nt * 64 + c4);
        t[kk][c4 + 0] = v.x;
        t[kk][c4 + 1] = v.y;
        t[kk][c4 + 2] = v.z;
        t[kk][c4 + 3] = v.w;
    }
    __syncthreads();
#pragma unroll
    for (int s = 0; s < 4; ++s) {
        const int nn = r + s * 16;
        unsigned int hv[2], lv[2];
#pragma unroll
        for (int p = 0; p < 2; ++p) {
            u16 h0, h1, l0, l1;
            float x0 = t[c4 + 2 * p][nn];
            float x1 = t[c4 + 2 * p + 1][nn];
            h0 = f2bf_rn(x0); l0 = f2bf_rn(x0 - bf2f(h0));
            h1 = f2bf_rn(x1); l1 = f2bf_rn(x1 - bf2f(h1));
            hv[p] = (unsigned int)h0 | ((unsigned int)h1 << 16);
            lv[p] = (unsigned int)l0 | ((unsigned int)l1 << 16);
        }
        u16* ph = Th + (size_t)(nt * 64 + nn) * K + kt * 64 + c4;
        u16* pl = Tl + (size_t)(nt * 64 + nn) * K + kt * 64 + c4;
        *(uint2*)ph = make_uint2(hv[0], hv[1]);
        *(uint2*)pl = make_uint2(lv[0], lv[1]);
    }
}

// ---------------------------------------------------------------------------
// Split-bf16 MFMA GEMM tile (verified R3): C = A @ B^T, 128x128, 4 waves.
// ---------------------------------------------------------------------------
__device__ __forceinline__ void mfma_gemm_tile(
    const u16* __restrict__ Ah, const u16* __restrict__ Al,
    const u16* __restrict__ Bh, const u16* __restrict__ Bl,
    float* __restrict__ C, const int Kd, const int ldc,
    const int bm0, const int bn0)
{
    __shared__ u16 ldsAh[128 * 32];
    __shared__ u16 ldsAl[128 * 32];
    __shared__ u16 ldsBh[128 * 32];
    __shared__ u16 ldsBl[128 * 32];

    const int tid  = threadIdx.x;
    const int lane = tid & 63;
    const int w    = tid >> 6;
    const int wr   = w >> 1, wc = w & 1;

    const int rs = tid >> 2;
    const int qs = (tid & 3) * 8;

    const u16* pAh = Ah + (size_t)(bm0 + rs) * Kd + qs;
    const u16* pAl = Al + (size_t)(bm0 + rs) * Kd + qs;
    const u16* pBh = Bh + (size_t)(bn0 + rs) * Kd + qs;
    const u16* pBl = Bl + (size_t)(bn0 + rs) * Kd + qs;
    const size_t rowskip = (size_t)64 * Kd;

    f32x4 acc[4][4];
#pragma unroll
    for (int i = 0; i < 4; ++i)
#pragma unroll
        for (int j = 0; j < 4; ++j) acc[i][j] = (f32x4){0.f, 0.f, 0.f, 0.f};

    const int fr = lane & 15;
    const int kb = (lane >> 4) * 8;

    for (int k0 = 0; k0 < Kd; k0 += 32) {
        uint4 sAh0 = *(const uint4*)(pAh);
        uint4 sAh1 = *(const uint4*)(pAh + rowskip);
        uint4 sAl0 = *(const uint4*)(pAl);
        uint4 sAl1 = *(const uint4*)(pAl + rowskip);
        uint4 sBh0 = *(const uint4*)(pBh);
        uint4 sBh1 = *(const uint4*)(pBh + rowskip);
        uint4 sBl0 = *(const uint4*)(pBl);
        uint4 sBl1 = *(const uint4*)(pBl + rowskip);
        pAh += 32; pAl += 32; pBh += 32; pBl += 32;

        if (k0) __syncthreads();
        *(uint4*)&ldsAh[rs * 32 + qs]        = sAh0;
        *(uint4*)&ldsAh[(rs + 64) * 32 + qs] = sAh1;
        *(uint4*)&ldsAl[rs * 32 + qs]        = sAl0;
        *(uint4*)&ldsAl[(rs + 64) * 32 + qs] = sAl1;
        *(uint4*)&ldsBh[rs * 32 + qs]        = sBh0;
        *(uint4*)&ldsBh[(rs + 64) * 32 + qs] = sBh1;
        *(uint4*)&ldsBl[rs * 32 + qs]        = sBl0;
        *(uint4*)&ldsBl[(rs + 64) * 32 + qs] = sBl1;
        __syncthreads();

        short8v a_h[4], a_l[4], b_h[4], b_l[4];
#pragma unroll
        for (int f = 0; f < 4; ++f) {
            const int ra = (wr * 64 + f * 16 + fr) * 32 + kb;
            const int rb = (wc * 64 + f * 16 + fr) * 32 + kb;
            a_h[f] = *(const short8v*)&ldsAh[ra];
            a_l[f] = *(const short8v*)&ldsAl[ra];
            b_h[f] = *(const short8v*)&ldsBh[rb];
            b_l[f] = *(const short8v*)&ldsBl[rb];
        }
#pragma unroll
        for (int i = 0; i < 4; ++i)
#pragma unroll
            for (int j = 0; j < 4; ++j) {
                acc[i][j] = __builtin_amdgcn_mfma_f32_16x16x32_bf16(a_h[i], b_h[j], acc[i][j], 0, 0, 0);
                acc[i][j] = __builtin_amdgcn_mfma_f32_16x16x32_bf16(a_h[i], b_l[j], acc[i][j], 0, 0, 0);
                acc[i][j] = __builtin_amdgcn_mfma_f32_16x16x32_bf16(a_l[i], b_h[j], acc[i][j], 0, 0, 0);
            }
    }

    const int cr = (lane >> 4) * 4;
    const int cc = lane & 15;
#pragma unroll
    for (int i = 0; i < 4; ++i)
#pragma unroll
        for (int j = 0; j < 4; ++j) {
#pragma unroll
            for (int r = 0; r < 4; ++r) {
                C[(size_t)(bm0 + wr * 64 + i * 16 + cr + r) * ldc
                  + (bn0 + wc * 64 + j * 16 + cc)] = acc[i][j][r];
            }
        }
}

__global__ __launch_bounds__(256, 2) void qkv_mfma_kernel(
    const u16* __restrict__ Xh, const u16* __restrict__ Xl,
    const u16* __restrict__ WqTh, const u16* __restrict__ WqTl,
    const u16* __restrict__ WkTh, const u16* __restrict__ WkTl,
    const u16* __restrict__ WvTh, const u16* __restrict__ WvTl,
    float* __restrict__ Qo, float* __restrict__ Ko, float* __restrict__ Vo)
{
    const int bn = blockIdx.x;
    const u16 *Bh, *Bl; float* C; int ldc, col0;
    if (bn < 16)      { Bh = WqTh; Bl = WqTl; C = Qo; ldc = NQ_;  col0 = bn * 128; }
    else if (bn < 18) { Bh = WkTh; Bl = WkTl; C = Ko; ldc = NKV_; col0 = (bn - 16) * 128; }
    else              { Bh = WvTh; Bl = WvTl; C = Vo; ldc = NKV_; col0 = (bn - 18) * 128; }
    mfma_gemm_tile(Xh, Xl, Bh, Bl, C, D_, ldc, blockIdx.y * 128, col0);
}

__global__ __launch_bounds__(256, 2) void out_mfma_kernel(
    const u16* __restrict__ Ch, const u16* __restrict__ Cl,
    const u16* __restrict__ WoTh, const u16* __restrict__ WoTl,
    float* __restrict__ Out)
{
    mfma_gemm_tile(Ch, Cl, WoTh, WoTl, Out, NQ_, D_, blockIdx.y * 128, blockIdx.x * 128);
}

// ---------------------------------------------------------------------------
// RoPE + split Q: Qw fp32 -> Qh/Ql bf16.  One block per row, 128 threads.
// ---------------------------------------------------------------------------
__global__ __launch_bounds__(128) void rope_split_q_kernel(
    const float* __restrict__ Qw, u16* __restrict__ Qh, u16* __restrict__ Ql)
{
    const int row = blockIdx.x;
    const int d = threadIdx.x;
    const int s = row & (S_ - 1);

    const float expo = (float)(2 * d) / (float)HD_;
    const float inv_freq = 1.0f / powf(10000.0f, expo);
    float sn, c;
    sincosf((float)s * inv_freq, &sn, &c);

    const float* qr = Qw + (size_t)row * NQ_;
    u16* qhr = Qh + (size_t)row * NQ_;
    u16* qlr = Ql + (size_t)row * NQ_;
#pragma unroll
    for (int h = 0; h < H_; ++h) {
        float x0 = qr[h * HD_ + d];
        float x1 = qr[h * HD_ + d + 128];
        float y0 = x0 * c - x1 * sn;
        float y1 = x1 * c + x0 * sn;
        u16 h0 = f2bf_rn(y0), h1 = f2bf_rn(y1);
        qhr[h * HD_ + d]       = h0;
        qhr[h * HD_ + d + 128] = h1;
        qlr[h * HD_ + d]       = f2bf_rn(y0 - bf2f(h0));
        qlr[h * HD_ + d + 128] = f2bf_rn(y1 - bf2f(h1));
    }
}

// RoPE + split K: Kw fp32 [4096][256] -> Kh/Kl bf16.
__global__ __launch_bounds__(128) void rope_split_k_kernel(
    const float* __restrict__ Kw, u16* __restrict__ Kh, u16* __restrict__ Kl)
{
    const int row = blockIdx.x;
    const int d = threadIdx.x;
    const int s = row & (S_ - 1);

    const float expo = (float)(2 * d) / (float)HD_;
    const float inv_freq = 1.0f / powf(10000.0f, expo);
    float sn, c;
    sincosf((float)s * inv_freq, &sn, &c);

    const float* kr = Kw + (size_t)row * HD_;
    float x0 = kr[d], x1 = kr[d + 128];
    float y0 = x0 * c - x1 * sn;
    float y1 = x1 * c + x0 * sn;
    u16 h0 = f2bf_rn(y0), h1 = f2bf_rn(y1);
    Kh[(size_t)row * HD_ + d]       = h0;
    Kh[(size_t)row * HD_ + d + 128] = h1;
    Kl[(size_t)row * HD_ + d]       = f2bf_rn(y0 - bf2f(h0));
    Kl[(size_t)row * HD_ + d + 128] = f2bf_rn(y1 - bf2f(h1));
}

// ---------------------------------------------------------------------------
// MFMA flash attention, split-bf16, causal, GQA(KV=1).
// QBLK=64 (4 waves x 16 q-rows), KVBLK=32, HD=256.
// K tile: LDS [32][256] u16 x2, XOR-swizzled (chunk ^= row&7).
// Vt tile: LDS [256][40] u16 x2 (pad 8) — shares buffer with K (phases).
// P: LDS [64][40] u16 x2, per-wave-private stripes (no barrier needed).
// ---------------------------------------------------------------------------
#define KVB_ 32

__global__ __launch_bounds__(256, 2) void attn_mfma_kernel(
    const u16* __restrict__ Qh, const u16* __restrict__ Ql,
    const u16* __restrict__ Kh, const u16* __restrict__ Kl,
    const u16* __restrict__ VtH, const u16* __restrict__ VtL,
    float* __restrict__ O)
{
    __shared__ u16 kv[2 * 256 * 40];   // 40960 B: K phase uses 2*8192 u16
    __shared__ u16 pb[2 * 64 * 40];    // 10240 B

    const int tid = threadIdx.x;
    const int lane = tid & 63;
    const int w = tid >> 6;

    // balanced (qt, bh) decode — same pairing as verified scalar kernel
    const int u = blockIdx.x & 255;
    const int pair = blockIdx.x >> 8;
    const int qt_base = u & 31;
    const int qt = pair ? (31 - qt_base) : qt_base;
    const int bh = (u >> 5) + pair * 8;
    const int b = bh >> 3, h = bh & 7;

    const int fr = lane & 15;          // frag row / col selector
    const int kq = (lane >> 4);        // k-chunk selector 0..3
    const int xm = fr & 7;             // XOR mask for K LDS

    // ---- Q fragments (hi/lo) to registers, loop-invariant ----
    short8v qfh[8], qfl[8];
    {
        const size_t qrow = (size_t)(b * S_ + qt * 64 + w * 16 + fr);
        const u16* ph = Qh + qrow * NQ_ + h * HD_ + kq * 8;
        const u16* pl = Ql + qrow * NQ_ + h * HD_ + kq * 8;
#pragma unroll
        for (int ks = 0; ks < 8; ++ks) {
            qfh[ks] = *(const short8v*)(ph + ks * 32);
            qfl[ks] = *(const short8v*)(pl + ks * 32);
        }
    }

    f32x4 oacc[16];
#pragma unroll
    for (int f = 0; f < 16; ++f) oacc[f] = (f32x4){0.f, 0.f, 0.f, 0.f};
    float m_i[4] = {-1e30f, -1e30f, -1e30f, -1e30f};
    float l_i[4] = {0.f, 0.f, 0.f, 0.f};

    const u16* ksrc[2] = {Kh + (size_t)b * S_ * HD_, Kl + (size_t)b * S_ * HD_};
    const u16* vsrc[2] = {VtH + (size_t)b * HD_ * S_, VtL + (size_t)b * HD_ * S_};

    const int nkt = (qt + 1) * 2;

    // ---- stage K tile kt=0 ----
#pragma unroll
    for (int c = 0; c < 2; ++c) {
        const u16* s = ksrc[c];
#pragma unroll
        for (int i = 0; i < 4; ++i) {
            const int chunk = i * 256 + tid;
            const int row = chunk >> 5, ch = chunk & 31;
            uint4 v = *(const uint4*)(s + (size_t)row * HD_ + ch * 8);
            *(uint4*)&kv[c * 8192 + row * 256 + (ch ^ (row & 7)) * 8] = v;
        }
    }
    __syncthreads();

    for (int kt = 0; kt < nkt; ++kt) {
        // ---- QK^T: 2 n-frags, 8 k-steps, 3-term split ----
        f32x4 s0 = (f32x4){0.f, 0.f, 0.f, 0.f};
        f32x4 s1 = (f32x4){0.f, 0.f, 0.f, 0.f};
#pragma unroll
        for (int ks = 0; ks < 8; ++ks) {
            const int ch = (ks * 4 + kq) ^ xm;
            short8v kh0 = *(const short8v*)&kv[fr * 256 + ch * 8];
            short8v kh1 = *(const short8v*)&kv[(16 + fr) * 256 + ch * 8];
            short8v kl0 = *(const short8v*)&kv[8192 + fr * 256 + ch * 8];
            short8v kl1 = *(const short8v*)&kv[8192 + (16 + fr) * 256 + ch * 8];
            s0 = __builtin_amdgcn_mfma_f32_16x16x32_bf16(qfh[ks], kh0, s0, 0, 0, 0);
            s1 = __builtin_amdgcn_mfma_f32_16x16x32_bf16(qfh[ks], kh1, s1, 0, 0, 0);
            s0 = __builtin_amdgcn_mfma_f32_16x16x32_bf16(qfh[ks], kl0, s0, 0, 0, 0);
            s1 = __builtin_amdgcn_mfma_f32_16x16x32_bf16(qfh[ks], kl1, s1, 0, 0, 0);
            s0 = __builtin_amdgcn_mfma_f32_16x16x32_bf16(qfl[ks], kh0, s0, 0, 0, 0);
            s1 = __builtin_amdgcn_mfma_f32_16x16x32_bf16(qfl[ks], kh1, s1, 0, 0, 0);
        }

        // ---- online softmax (rows r: q = (lane>>4)*4 + r) + P write ----
        const int qglob = qt * 64 + w * 16 + kq * 4;
        const int kg = kt * KVB_ + fr;
#pragma unroll
        for (int r = 0; r < 4; ++r) {
            float x0 = s0[r] * 0.0625f;
            float x1 = s1[r] * 0.0625f;
            if (kg > qglob + r)      x0 = -1e30f;
            if (kg + 16 > qglob + r) x1 = -1e30f;
            float mx = fmaxf(x0, x1);
#pragma unroll
            for (int off = 1; off < 16; off <<= 1)
                mx = fmaxf(mx, __shfl_xor(mx, off, 64));
            const float mnew = fmaxf(m_i[r], mx);
            const float alpha = __expf(m_i[r] - mnew);
            const float p0 = __expf(x0 - mnew);
            const float p1 = __expf(x1 - mnew);
            float ps = p0 + p1;
#pragma unroll
            for (int off = 1; off < 16; off <<= 1)
                ps += __shfl_xor(ps, off, 64);
            l_i[r] = l_i[r] * alpha + ps;
            m_i[r] = mnew;
#pragma unroll
            for (int f = 0; f < 16; ++f) oacc[f][r] *= alpha;

            const int prow = (w * 16 + kq * 4 + r) * 40;
            u16 h0 = f2bf_rn(p0), h1 = f2bf_rn(p1);
            pb[prow + fr]             = h0;
            pb[prow + 16 + fr]        = h1;
            pb[2560 + prow + fr]      = f2bf_rn(p0 - bf2f(h0));
            pb[2560 + prow + 16 + fr] = f2bf_rn(p1 - bf2f(h1));
        }
        __syncthreads();   // all waves done reading K tile

        // ---- stage Vt tile into shared buffer ----
#pragma unroll
        for (int c = 0; c < 2; ++c) {
            const u16* s = vsrc[c] + (size_t)kt * KVB_;
#pragma unroll
            for (int i = 0; i < 4; ++i) {
                const int chunk = i * 256 + tid;
                const int d = chunk >> 2, ch = chunk & 3;
                uint4 v = *(const uint4*)(s + (size_t)d * S_ + ch * 8);
                *(uint4*)&kv[c * 10240 + d * 40 + ch * 8] = v;
            }
        }
        __syncthreads();

        // ---- PV: A = P (own stripe), B = Vt frags ----
        {
            short8v pah = *(const short8v*)&pb[(w * 16 + fr) * 40 + kq * 8];
            short8v pal = *(const short8v*)&pb[2560 + (w * 16 + fr) * 40 + kq * 8];
#pragma unroll
            for (int f = 0; f < 16; ++f) {
                const int vrow = (f * 16 + fr) * 40 + kq * 8;
                short8v vh = *(const short8v*)&kv[vrow];
                short8v vl = *(const short8v*)&kv[10240 + vrow];
                oacc[f] = __builtin_amdgcn_mfma_f32_16x16x32_bf16(pah, vh, oacc[f], 0, 0, 0);
                oacc[f] = __builtin_amdgcn_mfma_f32_16x16x32_bf16(pal, vh, oacc[f], 0, 0, 0);
                oacc[f] = __builtin_amdgcn_mfma_f32_16x16x32_bf16(pah, vl, oacc[f], 0, 0, 0);
            }
        }
        __syncthreads();   // all waves done reading Vt

        // ---- stage next K tile ----
        if (kt + 1 < nkt) {
#pragma unroll
            for (int c = 0; c < 2; ++c) {
                const u16* s = ksrc[c] + (size_t)(kt + 1) * KVB_ * HD_;
#pragma unroll
                for (int i = 0; i < 4; ++i) {
                    const int chunk = i * 256 + tid;
                    const int row = chunk >> 5, ch = chunk & 31;
                    uint4 v = *(const uint4*)(s + (size_t)row * HD_ + ch * 8);
                    *(uint4*)&kv[c * 8192 + row * 256 + (ch ^ (row & 7)) * 8] = v;
                }
            }
            __syncthreads();
        }
    }

    // ---- epilogue: O = oacc / l ----
    float* orow = O + (size_t)(b * S_ + qt * 64 + w * 16 + kq * 4) * NQ_ + h * HD_ + fr;
#pragma unroll
    for (int r = 0; r < 4; ++r) {
        const float inv_l = 1.0f / l_i[r];
#pragma unroll
        for (int f = 0; f < 16; ++f)
            orow[(size_t)r * NQ_ + f * 16] = oacc[f][r] * inv_l;
    }
}

// ---------------------------------------------------------------------------
extern "C" void kernel_launch(void* const* d_in, const int* in_sizes, int n_in,
                              void* d_out, int out_size, void* d_ws, size_t ws_size,
                              hipStream_t stream)
{
    (void)in_sizes; (void)n_in; (void)out_size; (void)ws_size;

    const float* hidden = (const float*)d_in[0];
    const float* Wq = (const float*)d_in[3];
    const float* Wk = (const float*)d_in[4];
    const float* Wv = (const float*)d_in[5];
    const float* Wo = (const float*)d_in[6];
    float* out = (float*)d_out;

    char* ws = (char*)d_ws;
    // Region map (130 MB total, all reuse verified for hazards):
    //   [0, 33.5M)    : Qw fp32 — after rope_split_q consumed, holds Kh/Kl/Vt bf16
    float* Qw = (float*)(ws + 0);
    u16* Kh2 = (u16*)(ws + 0);               // 4096x256 u16 = 2 MB
    u16* Kl2 = (u16*)(ws + 2097152u);
    u16* VtH = (u16*)(ws + 4194304u);        // 2x256x2048 u16 = 2 MB
    u16* VtL = (u16*)(ws + 6291456u);
    float* Kw = (float*)(ws + 33554432u);    // 4096x256 fp32
    float* Vw = (float*)(ws + 37748736u);
    float* Cw = (float*)(ws + 41943040u);    // 4096x2048 fp32
    u16* Ah  = (u16*)(ws + 75497472u);       // X-split, then Qh, then Cw-split
    u16* Al  = (u16*)(ws + 92274688u);
    u16* WqTh = (u16*)(ws + 109051904u);
    u16* WqTl = (u16*)(ws + 117440512u);
    u16* WkTh = (u16*)(ws + 125829120u);
    u16* WkTl = (u16*)(ws + 126877696u);
    u16* WvTh = (u16*)(ws + 127926272u);
    u16* WvTl = (u16*)(ws + 128974848u);
    u16* WoTh = WqTh;
    u16* WoTl = WqTl;
    u16* Qhb = Ah;   // RoPE'd Q hi/lo reuse the X-split region (dead after QKV)
    u16* Qlb = Al;

    // 1) split X
    split_kernel<<<dim3((M_ * D_) / (256 * 8)), dim3(256), 0, stream>>>(hidden, Ah, Al);

    // 2) transpose+split weights
    tsplit_kernel<<<dim3(D_ / 64, NQ_ / 64),  dim3(256), 0, stream>>>(Wq, WqTh, WqTl, D_, NQ_);
    tsplit_kernel<<<dim3(D_ / 64, NKV_ / 64), dim3(256), 0, stream>>>(Wk, WkTh, WkTl, D_, NKV_);
    tsplit_kernel<<<dim3(D_ / 64, NKV_ / 64), dim3(256), 0, stream>>>(Wv, WvTh, WvTl, D_, NKV_);

    // 3) QKV projection (split-bf16 MFMA)
    qkv_mfma_kernel<<<dim3(20, M_ / 128), dim3(256), 0, stream>>>(
        Ah, Al, WqTh, WqTl, WkTh, WkTl, WvTh, WvTl, Qw, Kw, Vw);

    // 4) RoPE + split Q (Qw -> Qhb/Qlb; X-split now dead)
    rope_split_q_kernel<<<dim3(M_), dim3(128), 0, stream>>>(Qw, Qhb, Qlb);

    // 5) RoPE + split K (Kw -> Kh2/Kl2 in the now-dead Qw region)
    rope_split_k_kernel<<<dim3(M_), dim3(128), 0, stream>>>(Kw, Kh2, Kl2);

    // 6) transpose+split V per batch (Vw -> VtH/VtL)
    tsplit_kernel<<<dim3(S_ / 64, NKV_ / 64), dim3(256), 0, stream>>>(
        Vw, VtH, VtL, S_, NKV_);
    tsplit_kernel<<<dim3(S_ / 64, NKV_ / 64), dim3(256), 0, stream>>>(
        Vw + (size_t)S_ * NKV_, VtH + (size_t)HD_ * S_, VtL + (size_t)HD_ * S_, S_, NKV_);

    // 7) MFMA flash attention
    attn_mfma_kernel<<<dim3(512), dim3(256), 0, stream>>>(
        Qhb, Qlb, Kh2, Kl2, VtH, VtL, Cw);

    // 8) split context
    split_kernel<<<dim3((M_ * NQ_) / (256 * 8)), dim3(256), 0, stream>>>(Cw, Ah, Al);

    // 9) transpose+split Wo
    tsplit_kernel<<<dim3(NQ_ / 64, D_ / 64), dim3(256), 0, stream>>>(Wo, WoTh, WoTl, NQ_, D_);

    // 10) output projection
    out_mfma_kernel<<<dim3(D_ / 128, M_ / 128), dim3(256), 0, stream>>>(
        Ah, Al, WoTh, WoTl, out);
}